// Round 10
// baseline (103.274 us; speedup 1.0000x reference)
//
#include <hip/hip_runtime.h>

#define N 8192
#define D 128
#define CHUNK 512
#define NCC (N / CHUNK)        // 16 column chunks
#define NHT 8                  // 64-col half-tiles per chunk
#define NBIN 81                // labels -1..79 -> bins 0..80
#define PBLK 512               // prep grid (16 rows/block)

typedef unsigned short u16;
typedef __attribute__((ext_vector_type(8))) __bf16 bf16x8;
typedef __attribute__((ext_vector_type(4))) float f32x4;

// scale = sqrt(10 * log2(e)): dot of two scaled rows = log2(e^{cos/T}),
// so e^{sim} = exp2(acc) with NO per-element multiply.
#define PREP_SCALE 3.7982889979f

__device__ __forceinline__ u16 f2bf(float x) {
  unsigned u = __float_as_uint(x);
  u += 0x7fff + ((u >> 16) & 1);  // RNE
  return (u16)(u >> 16);
}

// ---- kernel 1: parallel counting-sort rank + normalize + bf16 write --------
// Each of 512 blocks independently histograms ALL labels (32 KB, L1-resident)
// + a partial histogram over j < myBase -> exact stable sorted position for
// its 16 rows. No cross-block state, no serial block (R1's 22us lesson).
// Single-bf16 (no lo split): R4-R9 measured absmax 0.0 with this math.
// Block 0 re-zeroes acc3 (re-poison safe).
__global__ __launch_bounds__(256) void cpe_prep(const float* __restrict__ feat,
                                                const int* __restrict__ labels,
                                                u16* __restrict__ fhi,
                                                int* __restrict__ slab,
                                                float* __restrict__ acc3) {
  __shared__ int hist[4][NBIN], part[4][NBIN], lbase[NBIN], lpos[16];
  const int tid = threadIdx.x;
  const int w = tid >> 6, l = tid & 63;
  const int bid = blockIdx.x;
  if (tid < NBIN) {
#pragma unroll
    for (int cp = 0; cp < 4; ++cp) { hist[cp][tid] = 0; part[cp][tid] = 0; }
  }
  if (bid == 0 && tid < 4) acc3[tid] = 0.0f;
  __syncthreads();
  const int myBase = bid * 16;  // this block's 16 ORIGINAL rows
  for (int j = tid; j < N; j += 256) {
    const int lab = labels[j] + 1;  // 0..80
    atomicAdd(&hist[w][lab], 1);
    if (j < myBase) atomicAdd(&part[w][lab], 1);
  }
  __syncthreads();
  if (tid < NBIN) {
    hist[0][tid] += hist[1][tid] + hist[2][tid] + hist[3][tid];
    part[0][tid] += part[1][tid] + part[2][tid] + part[3][tid];
  }
  __syncthreads();
  if (tid == 0) {  // exclusive scan of 81 bins — trivial
    int s = 0;
    for (int b = 0; b < NBIN; ++b) { lbase[b] = s; s += hist[0][b]; }
  }
  __syncthreads();
  if (tid < 16) {  // stable rank -> unique sorted position per row
    const int L = labels[myBase + tid] + 1;
    int pos = lbase[L] + part[0][L];
    for (int k = 0; k < tid; ++k) pos += (labels[myBase + k] + 1 == L) ? 1 : 0;
    lpos[tid] = pos;
    slab[pos] = L - 1;
  }
  __syncthreads();
#pragma unroll
  for (int rr = 0; rr < 4; ++rr) {  // one wave per row, 4 rows per wave
    const int k = w * 4 + rr;
    const float2 x = *(const float2*)&feat[(myBase + k) * D + l * 2];
    float s = x.x * x.x + x.y * x.y;
#pragma unroll
    for (int sh = 1; sh < 64; sh <<= 1) s += __shfl_xor(s, sh);
    const float inv = PREP_SCALE / fmaxf(sqrtf(s), 1e-12f);
    const int pos = lpos[k];
    *(ushort2*)&fhi[pos * D + l * 2] = make_ushort2(f2bf(x.x * inv), f2bf(x.y * inv));
  }
}

// ---- kernel 2: fused sim + masked reductions, 2-phase, 4 blocks/CU ---------
// vs R9 (31us, 66KB LDS -> 2 blocks/CU -> 8 waves/CU): stage 64-col
// HALF-TILES. Bh[2][64x128] (32KB) + Lab (2KB) = 34KB -> 4 blocks/CU,
// 16 waves/CU (VGPR 96 <= 128). Execution floor is ~15us (VALU-bound,
// pipes overlapped per m114); the ~16us residual stall in R9 was too few
// waves to cover barrier drains. Same 2-phase discipline: STAGE(next) is
// issued BEFORE computing current; one vmcnt-drain barrier per half-tile,
// covered by 4 ct-tiles (~500cyc) of MFMA+exp2 + 3 sibling blocks.
// SORTED label order: ~97% of 16-col tiles take the {exp2, add} fast path;
// all-bg tiles skip MFMA. loss = log(as/ps) (mxe/clips provably inactive).
__global__ __launch_bounds__(256, 2) void cpe_main(
    const u16* __restrict__ fhi, const int* __restrict__ slab,
    float2* __restrict__ partials) {
  __shared__ __align__(16) u16 Bh[2][64 * 128];  // 2 x 16 KB, XOR-swizzled
  __shared__ int Lab[CHUNK];                     // 2 KB
  const int rt = blockIdx.x, cc = blockIdx.y;
  const int tid = threadIdx.x;
  const int w = tid >> 6, l = tid & 63, q = l >> 4, m = l & 15;
  const int r0w = rt * 256 + w * 64;
  const int cbase0 = cc * CHUNK;

  // stage a 64-col half-tile: global->LDS DMA, 16B/lane, swizzle via the
  // GLOBAL addr. LDS slot p = w*256 + n*64 + lane -> (r = p>>4 in 0..63,
  // c' = p&15 = m); global col-group c = c' ^ (r & 15).
#define STAGE(buf, ht)                                                         \
  do {                                                                         \
    const int cb_ = cbase0 + (ht) * 64;                                        \
    _Pragma("unroll") for (int n = 0; n < 4; ++n) {                            \
      const int r_ = w * 16 + n * 4 + q;                                       \
      const int c_ = m ^ (r_ & 15);                                            \
      const u16* gh_ = &fhi[(size_t)(cb_ + r_) * D + c_ * 8];                  \
      __builtin_amdgcn_global_load_lds(                                        \
          (const __attribute__((address_space(1))) unsigned*)gh_,              \
          (__attribute__((address_space(3))) unsigned*)&Bh[buf][(w * 256 + n * 64) * 8], \
          16, 0, 0);                                                           \
    }                                                                          \
  } while (0)

  STAGE(0, 0);  // prologue: half-tile 0 in flight while Lab/A-frags load

  Lab[tid] = slab[cbase0 + tid];
  Lab[tid + 256] = slab[cbase0 + 256 + tid];

  // wave-uniform row-label range (labels sorted ascending)
  const int labi_lo = slab[r0w], labi_hi = slab[r0w + 63];

  // A fragments + row labels straight from global (L2-resident, once)
  bf16x8 Ah[4][4];
  int labi[4][4];
#pragma unroll
  for (int tr = 0; tr < 4; ++tr) {
    const int row = r0w + tr * 16 + m;
#pragma unroll
    for (int ks = 0; ks < 4; ++ks)
      Ah[tr][ks] = *(const bf16x8*)&fhi[row * D + ks * 32 + q * 8];
#pragma unroll
    for (int v = 0; v < 4; ++v) labi[tr][v] = slab[r0w + tr * 16 + q * 4 + v];
  }

  float ps[4][4], as_[4][4];
#pragma unroll
  for (int tr = 0; tr < 4; ++tr)
#pragma unroll
    for (int v = 0; v < 4; ++v) { ps[tr][v] = 0.f; as_[tr][v] = 0.f; }

  __syncthreads();  // Lab ready + half-tile 0 staged (vmcnt drained)

  for (int ht = 0; ht < NHT; ++ht) {
    const int cur = ht & 1;
    if (ht + 1 < NHT) STAGE(cur ^ 1, ht + 1);  // overlap: next half-tile DMA

    for (int ct = 0; ct < 4; ++ct) {
      const int tb = ht * 64 + ct * 16;
      const int labj_lo = Lab[tb], labj_hi = Lab[tb + 15];
      if (labj_hi < 0) continue;  // all-bg tile: every em==0, skip MFMA too
      const bool slow = (labj_lo < 0) | ((labj_hi >= labi_lo) & (labj_lo <= labi_hi));
      const int jj = ct * 16 + m;  // row within the 64-row half-tile buffer
      f32x4 acc[4];
#pragma unroll
      for (int tr = 0; tr < 4; ++tr) acc[tr] = (f32x4){0.f, 0.f, 0.f, 0.f};
#pragma unroll
      for (int ks = 0; ks < 4; ++ks) {
        const int off = jj * 128 + ((ks * 4 + q) ^ m) * 8;  // swizzled chunk
        const bf16x8 bh = *(const bf16x8*)&Bh[cur][off];
#pragma unroll
        for (int tr = 0; tr < 4; ++tr)
          acc[tr] = __builtin_amdgcn_mfma_f32_16x16x32_bf16(Ah[tr][ks], bh, acc[tr], 0, 0, 0);
      }
      if (!slow) {
        // fast path (~97% of tiles): all-fg, no positives, no self
#pragma unroll
        for (int tr = 0; tr < 4; ++tr)
#pragma unroll
          for (int v = 0; v < 4; ++v)
            as_[tr][v] += __builtin_amdgcn_exp2f(acc[tr][v]);
      } else {
        const int labj = Lab[tb + m];
        const bool fgj = labj >= 0;
        const int jbase = cbase0 + tb;
#pragma unroll
        for (int tr = 0; tr < 4; ++tr) {
          if (jbase == r0w + tr * 16) {  // wave-uniform diagonal-tile branch
#pragma unroll
            for (int v = 0; v < 4; ++v) {
              const float e = __builtin_amdgcn_exp2f(acc[tr][v]);
              const float em = (fgj && (m != q * 4 + v)) ? e : 0.0f;
              as_[tr][v] += em;
              ps[tr][v] += (labj == labi[tr][v]) ? em : 0.0f;
            }
          } else {
#pragma unroll
            for (int v = 0; v < 4; ++v) {
              const float e = __builtin_amdgcn_exp2f(acc[tr][v]);
              const float em = fgj ? e : 0.0f;
              as_[tr][v] += em;
              ps[tr][v] += (labj == labi[tr][v]) ? em : 0.0f;
            }
          }
        }
      }
    }
    // one barrier per half-tile: waves done reading Bh[cur] AND the next
    // half-tile's DMA drained — latency hidden under this half-tile's
    // compute and the 3 sibling blocks on this CU.
    __syncthreads();
  }
#undef STAGE

  // reduce across the 16 lanes (m) of each quad; plain float2 store per row
#pragma unroll
  for (int tr = 0; tr < 4; ++tr)
#pragma unroll
    for (int v = 0; v < 4; ++v) {
      float vp = ps[tr][v], va = as_[tr][v];
#pragma unroll
      for (int s = 1; s < 16; s <<= 1) {
        vp += __shfl_xor(vp, s);
        va += __shfl_xor(va, s);
      }
      if (m == 0)
        partials[(size_t)cc * N + r0w + tr * 16 + q * 4 + v] = make_float2(vp, va);
    }
}

// ---- kernel 3: combine partials -> per-row loss -> mean (self-finalizing) --
// R0-proven pattern (~4us). Cross-dispatch visibility of partials is free
// (kernel-boundary release/acquire) — no fences needed.
__global__ __launch_bounds__(256) void cpe_rows(const float2* __restrict__ partials,
                                                const int* __restrict__ slab,
                                                float* __restrict__ acc3,
                                                float* __restrict__ out) {
  const int r = blockIdx.x * 256 + threadIdx.x;
  float psr = 0.f, asr = 0.f;
#pragma unroll
  for (int c = 0; c < NCC; ++c) {
    const float2 p = partials[(size_t)c * N + r];
    psr += p.x;
    asr += p.y;
  }
  const bool fg = slab[r] >= 0;
  const bool valid = fg && (psr > 0.f);  // e>0 => (npos>0 <=> ps>0)
  const float loss = fminf(logf(asr / psr), 10.0f);
  float v0 = valid ? loss : 0.f;
  float v1 = valid ? 1.f : 0.f;
  float v2 = fg ? 1.f : 0.f;
#pragma unroll
  for (int s = 1; s < 64; s <<= 1) {
    v0 += __shfl_xor(v0, s);
    v1 += __shfl_xor(v1, s);
    v2 += __shfl_xor(v2, s);
  }
  __shared__ float red[3][4];
  const int w = threadIdx.x >> 6, l = threadIdx.x & 63;
  if (l == 0) { red[0][w] = v0; red[1][w] = v1; red[2][w] = v2; }
  __syncthreads();
  if (threadIdx.x == 0) {
    atomicAdd(&acc3[0], red[0][0] + red[0][1] + red[0][2] + red[0][3]);
    atomicAdd(&acc3[1], red[1][0] + red[1][1] + red[1][2] + red[1][3]);
    atomicAdd(&acc3[2], red[2][0] + red[2][1] + red[2][2] + red[2][3]);
    __threadfence();
    const unsigned old = atomicAdd((unsigned*)&acc3[3], 1u);
    if (old == gridDim.x - 1) {  // last block finalizes (device-scope reads)
      const float ls = atomicAdd(&acc3[0], 0.0f);
      const float nv = atomicAdd(&acc3[1], 0.0f);
      const float nf = atomicAdd(&acc3[2], 0.0f);
      out[0] = (nf >= 2.0f && nv > 0.0f) ? ls / fmaxf(nv, 1.0f) : 0.0f;
    }
  }
}

extern "C" void kernel_launch(void* const* d_in, const int* in_sizes, int n_in,
                              void* d_out, int out_size, void* d_ws, size_t ws_size,
                              hipStream_t stream) {
  const float* feat = (const float*)d_in[0];
  const int* labels = (const int*)d_in[1];
  float* out = (float*)d_out;
  char* ws = (char*)d_ws;
  u16* fhi = (u16*)ws;                                    // 2 MB
  float2* partials = (float2*)(ws + (size_t)N * D * 2);   // 1 MB (16 chunks)
  char* tail = ws + (size_t)N * D * 2 + (size_t)NCC * N * 8;
  int* slab = (int*)tail;                                 // 32 KB
  float* acc3 = (float*)(tail + N * 4);                   // 4 f32

  cpe_prep<<<PBLK, 256, 0, stream>>>(feat, labels, fhi, slab, acc3);
  cpe_main<<<dim3(N / 256, NCC), 256, 0, stream>>>(fhi, slab, partials);
  cpe_rows<<<N / 256, 256, 0, stream>>>(partials, slab, acc3, out);
}